// Round 9
// baseline (443.212 us; speedup 1.0000x reference)
//
#include <hip/hip_runtime.h>
#include <hip/hip_bf16.h>

#define IN_DIM 1024
#define HID 512
#define OUTD 256

typedef __attribute__((ext_vector_type(8))) short short8;
typedef __attribute__((ext_vector_type(4))) float f32x4;
typedef __attribute__((ext_vector_type(8))) unsigned short ushort8e;
typedef __attribute__((ext_vector_type(4))) unsigned short ushort4e;

template<int F> struct VecSel;
template<> struct VecSel<8> { using T = ushort8e; };
template<> struct VecSel<4> { using T = ushort4e; };

// ---------------- helpers ----------------

__device__ inline unsigned short f2bf(float f) {
    union { float f; unsigned u; } v; v.f = f;
    unsigned r = (v.u + 0x7FFF + ((v.u >> 16) & 1)) >> 16;  // RNE
    return (unsigned short)r;
}

__device__ inline float bf2f(unsigned short u) {
    union { unsigned u; float f; } v; v.u = ((unsigned)u) << 16; return v.f;
}

__device__ inline void gload16(const void* g, void* l) {
    __builtin_amdgcn_global_load_lds(
        (const __attribute__((address_space(1))) void*)g,
        (__attribute__((address_space(3))) void*)l, 16, 0, 0);
}

// ---------------- degree / norm ----------------

__global__ void deg_kernel(const int* __restrict__ src, const int* __restrict__ dst,
                           int* __restrict__ dego, int* __restrict__ degi, int E) {
    int i = blockIdx.x * blockDim.x + threadIdx.x;
    if (i < E) {
        atomicAdd(&dego[src[i]], 1);
        atomicAdd(&degi[dst[i]], 1);
    }
}

__global__ void invsqrt_kernel(const int* __restrict__ dego, const int* __restrict__ degi,
                               float* __restrict__ iso, float* __restrict__ isi, int n) {
    int i = blockIdx.x * blockDim.x + threadIdx.x;
    if (i < n) {
        iso[i] = rsqrtf(fmaxf((float)dego[i], 1.0f));
        isi[i] = rsqrtf(fmaxf((float)degi[i], 1.0f));
    }
}

// ---------------- exclusive scan over N=65536 (256 blocks x 256) ----------------

__global__ __launch_bounds__(256) void scan_block(const int* __restrict__ deg,
                                                  int* __restrict__ excl,
                                                  int* __restrict__ partials) {
    __shared__ int tmp[256];
    int tid = threadIdx.x;
    int i = blockIdx.x * 256 + tid;
    int v = deg[i];
    tmp[tid] = v;
    __syncthreads();
    #pragma unroll
    for (int off = 1; off < 256; off <<= 1) {
        int t = (tid >= off) ? tmp[tid - off] : 0;
        __syncthreads();
        tmp[tid] += t;
        __syncthreads();
    }
    excl[i] = tmp[tid] - v;
    if (tid == 255) partials[blockIdx.x] = tmp[255];
}

__global__ __launch_bounds__(256) void scan_partials(int* __restrict__ partials) {
    __shared__ int tmp[256];
    int tid = threadIdx.x;
    int v = partials[tid];
    tmp[tid] = v;
    __syncthreads();
    #pragma unroll
    for (int off = 1; off < 256; off <<= 1) {
        int t = (tid >= off) ? tmp[tid - off] : 0;
        __syncthreads();
        tmp[tid] += t;
        __syncthreads();
    }
    partials[tid] = tmp[tid] - v;   // exclusive
}

__global__ __launch_bounds__(256) void scan_add(const int* __restrict__ excl,
                                                const int* __restrict__ partials,
                                                const int* __restrict__ deg,
                                                int* __restrict__ row_start,
                                                int* __restrict__ cursor, int n) {
    int i = blockIdx.x * 256 + threadIdx.x;
    int v = excl[i] + partials[blockIdx.x];
    row_start[i] = v;
    cursor[i] = v;
    if (i == n - 1) row_start[n] = v + deg[i];
}

__global__ void csr_fill(const int* __restrict__ src, const int* __restrict__ dst,
                         int* __restrict__ cursor, int* __restrict__ eidx, int E) {
    int e = blockIdx.x * blockDim.x + threadIdx.x;
    if (e < E) {
        int pos = atomicAdd(&cursor[dst[e]], 1);
        eidx[pos] = src[e];
    }
}

// ---------------- conversions ----------------

// y = bf16(x * rs[i>>logK]), grid-stride
__global__ __launch_bounds__(256) void scale_cvt(
    const float* __restrict__ x, const float* __restrict__ rs,
    unsigned short* __restrict__ y, int logK, size_t total)
{
    const size_t stride = (size_t)gridDim.x * 256 * 8;
    for (size_t i = ((size_t)blockIdx.x * 256 + threadIdx.x) * 8; i < total; i += stride) {
        float s = rs[i >> logK];
        float4 a = *reinterpret_cast<const float4*>(x + i);
        float4 b = *reinterpret_cast<const float4*>(x + i + 4);
        short8 o;
        o[0] = (short)f2bf(a.x * s); o[1] = (short)f2bf(a.y * s);
        o[2] = (short)f2bf(a.z * s); o[3] = (short)f2bf(a.w * s);
        o[4] = (short)f2bf(b.x * s); o[5] = (short)f2bf(b.y * s);
        o[6] = (short)f2bf(b.z * s); o[7] = (short)f2bf(b.w * s);
        *reinterpret_cast<short8*>(y + i) = o;
    }
}

__global__ void transpose_cvt(const float* __restrict__ W, unsigned short* __restrict__ Wt,
                              int K, int N) {
    int i = blockIdx.x * 256 + threadIdx.x;
    if (i < N * K) {
        int n = i / K, k = i - n * K;
        Wt[i] = f2bf(W[(size_t)k * N + n]);
    }
}

// ---------------- bf16 MFMA GEMM: C = A[M,K] @ Bt[Nc,K]^T, bf16 output ----------------
// m97-exact structure: BK=32, single-buffered, global_load_lds both operands,
// 2 barriers per K-step. 1-D grid + XCD-aware swizzle (siblings sharing an
// A-panel run consecutively on the same XCD -> panel is an L2 hit).

#define TM 128
#define TN 128
#define TK 32
#define NXCD 8

__global__ __launch_bounds__(256) void gemm_bf16_mfma(
    const unsigned short* __restrict__ A,   // [M][K] bf16
    const unsigned short* __restrict__ Bt,  // [Nc][K] bf16
    unsigned short* __restrict__ Cb,        // [M][Nc] bf16
    int M, int K, int Nc)
{
    __shared__ unsigned short As[TM][TK];   // 8 KB
    __shared__ unsigned short Bs[TN][TK];   // 8 KB

    const int tid  = threadIdx.x;
    const int lane = tid & 63;
    const int wave = tid >> 6;
    const int wr = wave >> 1, wc = wave & 1;
    const int lrow = lane & 15;
    const int lkg  = lane >> 4;

    // ---- XCD swizzle ----
    const int nwg = gridDim.x;                // divisible by 8
    const int per = nwg / NXCD;
    const int lin = blockIdx.x;
    const int newlin = (lin % NXCD) * per + lin / NXCD;
    const int ncb = Nc / TN;
    const int m0 = (newlin / ncb) * TM;
    const int n0 = (newlin % ncb) * TN;

    // staging: slot s (0..511) -> row s>>2, 16B quad; source quad XOR-swizzled
    const int s0 = wave * 64 + lane;
    const int s1 = s0 + 256;
    const int r0 = s0 >> 2, q0 = (s0 & 3) ^ ((s0 >> 3) & 3);
    const int r1 = s1 >> 2, q1 = (s1 & 3) ^ ((s1 >> 3) & 3);

    char* AsB = (char*)&As[0][0];
    char* BsB = (char*)&Bs[0][0];
    void* ldsA0 = AsB + wave * 1024;
    void* ldsA1 = AsB + 4096 + wave * 1024;
    void* ldsB0 = BsB + wave * 1024;
    void* ldsB1 = BsB + 4096 + wave * 1024;

    const int rslot = (lkg ^ ((lrow >> 1) & 3)) * 8;

    f32x4 acc[4][4] = {};

    const int nk = K / TK;
    for (int kt = 0; kt < nk; ++kt) {
        const int k0 = kt * TK;
        gload16(A  + (size_t)(m0 + r0) * K + k0 + q0 * 8, ldsA0);
        gload16(A  + (size_t)(m0 + r1) * K + k0 + q1 * 8, ldsA1);
        gload16(Bt + (size_t)(n0 + r0) * K + k0 + q0 * 8, ldsB0);
        gload16(Bt + (size_t)(n0 + r1) * K + k0 + q1 * 8, ldsB1);
        __syncthreads();

        short8 af[4], bfr[4];
        #pragma unroll
        for (int mi = 0; mi < 4; ++mi)
            af[mi] = *reinterpret_cast<const short8*>(&As[wr * 64 + mi * 16 + lrow][rslot]);
        #pragma unroll
        for (int ni = 0; ni < 4; ++ni)
            bfr[ni] = *reinterpret_cast<const short8*>(&Bs[wc * 64 + ni * 16 + lrow][rslot]);

        #pragma unroll
        for (int mi = 0; mi < 4; ++mi)
            #pragma unroll
            for (int ni = 0; ni < 4; ++ni)
                acc[mi][ni] = __builtin_amdgcn_mfma_f32_16x16x32_bf16(
                    af[mi], bfr[ni], acc[mi][ni], 0, 0, 0);

        __syncthreads();
    }

    #pragma unroll
    for (int mi = 0; mi < 4; ++mi)
        #pragma unroll
        for (int ni = 0; ni < 4; ++ni)
            #pragma unroll
            for (int r = 0; r < 4; ++r)
                Cb[(size_t)(m0 + wr * 64 + mi * 16 + lkg * 4 + r) * Nc
                   + (n0 + wc * 64 + ni * 16 + lrow)] = f2bf(acc[mi][ni][r]);
}

// ---------------- CSR gather-aggregate (bf16 X), fused epilogues ----------------
// One wave per node; lane owns DIM/64 contiguous elems. 4-edge unroll for MLP.

template<int DIM, bool LAYER1>
__global__ __launch_bounds__(256) void aggregate(
    const int* __restrict__ row_start, const int* __restrict__ eidx,
    const unsigned short* __restrict__ Xb, const float* __restrict__ isi,
    const float* __restrict__ iso, const float* __restrict__ bias,
    unsigned short* __restrict__ out_bf, float* __restrict__ out_f)
{
    constexpr int F = DIM / 64;           // 8 (HID) or 4 (OUTD)
    using VecT = typename VecSel<F>::T;
    const int node = blockIdx.x * 4 + (threadIdx.x >> 6);
    const int lane = threadIdx.x & 63;

    const int beg = row_start[node];
    const int end = row_start[node + 1];
    const unsigned short* base = Xb + lane * F;

    float acc[F] = {};
    int e = beg;
    for (; e + 3 < end; e += 4) {
        int i0 = eidx[e], i1 = eidx[e + 1], i2 = eidx[e + 2], i3 = eidx[e + 3];
        VecT v0 = *reinterpret_cast<const VecT*>(base + (size_t)i0 * DIM);
        VecT v1 = *reinterpret_cast<const VecT*>(base + (size_t)i1 * DIM);
        VecT v2 = *reinterpret_cast<const VecT*>(base + (size_t)i2 * DIM);
        VecT v3 = *reinterpret_cast<const VecT*>(base + (size_t)i3 * DIM);
        #pragma unroll
        for (int f = 0; f < F; ++f) {
            acc[f] += bf2f(v0[f]); acc[f] += bf2f(v1[f]);
            acc[f] += bf2f(v2[f]); acc[f] += bf2f(v3[f]);
        }
    }
    for (; e < end; ++e) {
        VecT v0 = *reinterpret_cast<const VecT*>(base + (size_t)eidx[e] * DIM);
        #pragma unroll
        for (int f = 0; f < F; ++f) acc[f] += bf2f(v0[f]);
    }

    const float si = isi[node];
    float bv[F];
    #pragma unroll
    for (int q = 0; q < F / 4; ++q)
        *reinterpret_cast<float4*>(&bv[q * 4]) =
            *reinterpret_cast<const float4*>(bias + lane * F + q * 4);

    if (LAYER1) {
        const float so = iso[node];
        short8 o;
        #pragma unroll
        for (int f = 0; f < F; ++f) {
            float v = acc[f] * si + bv[f];
            v = v > 0.f ? v : expm1f(v);
            o[f] = (short)f2bf(v * so);
        }
        *reinterpret_cast<short8*>(out_bf + (size_t)node * DIM + lane * F) = o;
    } else {
        #pragma unroll
        for (int q = 0; q < F / 4; ++q) {
            float4 v = make_float4(acc[q * 4 + 0] * si + bv[q * 4 + 0],
                                   acc[q * 4 + 1] * si + bv[q * 4 + 1],
                                   acc[q * 4 + 2] * si + bv[q * 4 + 2],
                                   acc[q * 4 + 3] * si + bv[q * 4 + 3]);
            *reinterpret_cast<float4*>(out_f + (size_t)node * DIM + lane * F + q * 4) = v;
        }
    }
}

// ---------------- launch ----------------

extern "C" void kernel_launch(void* const* d_in, const int* in_sizes, int n_in,
                              void* d_out, int out_size, void* d_ws, size_t ws_size,
                              hipStream_t stream) {
    const float* h  = (const float*)d_in[0];
    const float* W1 = (const float*)d_in[1];
    const float* b1 = (const float*)d_in[2];
    const float* W2 = (const float*)d_in[3];
    const float* b2 = (const float*)d_in[4];
    const int*   src = (const int*)d_in[5];
    const int*   dst = (const int*)d_in[6];

    const int N = in_sizes[0] / IN_DIM;   // 65536
    const int E = in_sizes[5];            // 524288
    float* out = (float*)d_out;

    // ---- workspace layout ----
    int* dego      = (int*)d_ws;                   // N
    int* degi      = dego + N;                     // N
    int* excl      = degi + N;                     // N
    int* partials  = excl + N;                     // 256
    int* row_start = partials + 256;               // N+1 (pad to N+64)
    int* cursor    = row_start + N + 64;           // N
    int* eidx      = cursor + N;                   // E
    float* iso     = (float*)(eidx + E);           // N
    float* isi     = iso + N;                      // N
    unsigned short* W1t = (unsigned short*)(isi + N);      // IN_DIM*HID
    unsigned short* W2t = W1t + (size_t)IN_DIM * HID;      // HID*OUTD
    unsigned short* hb  = W2t + (size_t)HID * OUTD;        // N*IN_DIM bf16 (134MB)
    unsigned short* X1b = hb + (size_t)N * IN_DIM;         // N*HID bf16 (67MB)
    unsigned short* X2b = X1b;                             // alias (X1 dead before gemm2 write)
    unsigned short* R2h = X1b + (size_t)N * HID;           // N*HID bf16 (67MB) — x1s

    hipMemsetAsync(dego, 0, sizeof(int) * (size_t)2 * N, stream);

    deg_kernel<<<(E + 255) / 256, 256, 0, stream>>>(src, dst, dego, degi, E);
    invsqrt_kernel<<<(N + 255) / 256, 256, 0, stream>>>(dego, degi, iso, isi, N);

    // CSR by dst
    scan_block<<<N / 256, 256, 0, stream>>>(degi, excl, partials);
    scan_partials<<<1, 256, 0, stream>>>(partials);
    scan_add<<<N / 256, 256, 0, stream>>>(excl, partials, degi, row_start, cursor, N);
    csr_fill<<<(E + 255) / 256, 256, 0, stream>>>(src, dst, cursor, eidx, E);

    // hb = bf16(iso ⊙ h); weights -> bf16 transposed
    scale_cvt<<<2048, 256, 0, stream>>>(h, iso, hb, 10, (size_t)N * IN_DIM);
    transpose_cvt<<<(IN_DIM * HID + 255) / 256, 256, 0, stream>>>(W1, W1t, IN_DIM, HID);
    transpose_cvt<<<(HID * OUTD + 255) / 256, 256, 0, stream>>>(W2, W2t, HID, OUTD);

    // Layer 1: X1b = bf16(hb @ W1) ; R2h = bf16(elu(agg(X1b)*isi + b1) * iso)
    gemm_bf16_mfma<<<(N / TM) * (HID / TN), 256, 0, stream>>>(
        hb, W1t, X1b, N, IN_DIM, HID);
    aggregate<HID, true><<<N / 4, 256, 0, stream>>>(
        row_start, eidx, X1b, isi, iso, b1, R2h, nullptr);

    // Layer 2: X2b = bf16(R2h @ W2) ; out = agg(X2b)*isi + b2
    gemm_bf16_mfma<<<(N / TM) * (OUTD / TN), 256, 0, stream>>>(
        R2h, W2t, X2b, N, HID, OUTD);
    aggregate<OUTD, false><<<N / 4, 256, 0, stream>>>(
        row_start, eidx, X2b, isi, iso, b2, nullptr, out);
}

// Round 10
// 431.719 us; speedup vs baseline: 1.0266x; 1.0266x over previous
//
#include <hip/hip_runtime.h>
#include <hip/hip_bf16.h>

#define IN_DIM 1024
#define HID 512
#define OUTD 256

typedef __attribute__((ext_vector_type(8))) short short8;
typedef __attribute__((ext_vector_type(4))) float f32x4;
typedef __attribute__((ext_vector_type(8))) unsigned short ushort8e;
typedef __attribute__((ext_vector_type(4))) unsigned short ushort4e;
typedef __attribute__((ext_vector_type(4))) unsigned int uint4e;

template<int F> struct VecSel;
template<> struct VecSel<8> { using T = ushort8e; };
template<> struct VecSel<4> { using T = ushort4e; };

// ---------------- helpers ----------------

__device__ inline unsigned short f2bf(float f) {
    union { float f; unsigned u; } v; v.f = f;
    unsigned r = (v.u + 0x7FFF + ((v.u >> 16) & 1)) >> 16;  // RNE
    return (unsigned short)r;
}

__device__ inline float bf2f(unsigned short u) {
    union { unsigned u; float f; } v; v.u = ((unsigned)u) << 16; return v.f;
}

// packed f32x2 -> bf16x2 via v_cvt_pk_bf16_f32 (low word = a)
__device__ inline unsigned pkbf(float a, float b) {
    __hip_bfloat162 h = __float22bfloat162_rn(float2{a, b});
    union { __hip_bfloat162 h; unsigned u; } v; v.h = h; return v.u;
}

__device__ inline void gload16(const void* g, void* l) {
    __builtin_amdgcn_global_load_lds(
        (const __attribute__((address_space(1))) void*)g,
        (__attribute__((address_space(3))) void*)l, 16, 0, 0);
}

// ---------------- degree / norm ----------------

__global__ void deg_kernel(const int* __restrict__ src, const int* __restrict__ dst,
                           int* __restrict__ dego, int* __restrict__ degi, int E) {
    int i = blockIdx.x * blockDim.x + threadIdx.x;
    if (i < E) {
        atomicAdd(&dego[src[i]], 1);
        atomicAdd(&degi[dst[i]], 1);
    }
}

__global__ void invsqrt_kernel(const int* __restrict__ dego, const int* __restrict__ degi,
                               float* __restrict__ iso, float* __restrict__ isi, int n) {
    int i = blockIdx.x * blockDim.x + threadIdx.x;
    if (i < n) {
        iso[i] = rsqrtf(fmaxf((float)dego[i], 1.0f));
        isi[i] = rsqrtf(fmaxf((float)degi[i], 1.0f));
    }
}

// ---------------- exclusive scan over N=65536 (256 blocks x 256) ----------------

__global__ __launch_bounds__(256) void scan_block(const int* __restrict__ deg,
                                                  int* __restrict__ excl,
                                                  int* __restrict__ partials) {
    __shared__ int tmp[256];
    int tid = threadIdx.x;
    int i = blockIdx.x * 256 + tid;
    int v = deg[i];
    tmp[tid] = v;
    __syncthreads();
    #pragma unroll
    for (int off = 1; off < 256; off <<= 1) {
        int t = (tid >= off) ? tmp[tid - off] : 0;
        __syncthreads();
        tmp[tid] += t;
        __syncthreads();
    }
    excl[i] = tmp[tid] - v;
    if (tid == 255) partials[blockIdx.x] = tmp[255];
}

__global__ __launch_bounds__(256) void scan_partials(int* __restrict__ partials) {
    __shared__ int tmp[256];
    int tid = threadIdx.x;
    int v = partials[tid];
    tmp[tid] = v;
    __syncthreads();
    #pragma unroll
    for (int off = 1; off < 256; off <<= 1) {
        int t = (tid >= off) ? tmp[tid - off] : 0;
        __syncthreads();
        tmp[tid] += t;
        __syncthreads();
    }
    partials[tid] = tmp[tid] - v;   // exclusive
}

__global__ __launch_bounds__(256) void scan_add(const int* __restrict__ excl,
                                                const int* __restrict__ partials,
                                                const int* __restrict__ deg,
                                                int* __restrict__ row_start,
                                                int* __restrict__ cursor, int n) {
    int i = blockIdx.x * 256 + threadIdx.x;
    int v = excl[i] + partials[blockIdx.x];
    row_start[i] = v;
    cursor[i] = v;
    if (i == n - 1) row_start[n] = v + deg[i];
}

__global__ void csr_fill(const int* __restrict__ src, const int* __restrict__ dst,
                         int* __restrict__ cursor, int* __restrict__ eidx, int E) {
    int e = blockIdx.x * blockDim.x + threadIdx.x;
    if (e < E) {
        int pos = atomicAdd(&cursor[dst[e]], 1);
        eidx[pos] = src[e];
    }
}

// ---------------- weight transpose+cvt ----------------

__global__ void transpose_cvt(const float* __restrict__ W, unsigned short* __restrict__ Wt,
                              int K, int N) {
    int i = blockIdx.x * 256 + threadIdx.x;
    if (i < N * K) {
        int n = i / K, k = i - n * K;
        Wt[i] = f2bf(W[(size_t)k * N + n]);
    }
}

// ---------------- bf16 MFMA GEMM: C = A[M,K] @ Bt[Nc,K]^T, bf16 output ----------------
// BK=64 double-buffered single-barrier K-loop, XCD-aware block swizzle.
// AF32=1: A f32, cvt to bf16 via v_cvt_pk in reg-staging (NO scale — moved to agg).
// AF32=0: A bf16 via global_load_lds.

#define TM 128
#define TN 128
#define TK 64
#define NXCD 8

template<int AF32>
__global__ __launch_bounds__(256) void gemm_bf16_mfma(
    const void* __restrict__ Ap, const unsigned short* __restrict__ Bt,
    unsigned short* __restrict__ Cb, int M, int K, int Nc)
{
    __shared__ unsigned short As[2][TM][TK];   // 2 x 16 KB
    __shared__ unsigned short Bs[2][TN][TK];   // 2 x 16 KB

    const int tid  = threadIdx.x;
    const int lane = tid & 63;
    const int wave = tid >> 6;
    const int wr = wave >> 1, wc = wave & 1;
    const int lrow = lane & 15;
    const int lkg  = lane >> 4;

    // ---- XCD swizzle: siblings sharing an A-panel run on the same XCD ----
    const int nwg = gridDim.x;                // divisible by 8
    const int per = nwg / NXCD;
    const int lin = blockIdx.x;
    const int newlin = (lin % NXCD) * per + lin / NXCD;
    const int ncb = Nc / TN;
    const int m0 = (newlin / ncb) * TM;
    const int n0 = (newlin % ncb) * TN;

    // gload_lds slot geometry: instr i covers slots s = i*256 + wave*64 + lane
    // slot s -> row = s>>3, phys quad = s&7, src logical quad = (s&7) ^ (row&7)
    int srow[4], sq[4];
    #pragma unroll
    for (int i = 0; i < 4; ++i) {
        int s = i * 256 + wave * 64 + lane;
        srow[i] = s >> 3;
        sq[i] = (s & 7) ^ ((s >> 3) & 7);
    }

    char* AsB = (char*)&As[0][0][0];
    char* BsB = (char*)&Bs[0][0][0];

    const float* Af = (const float*)Ap;
    const unsigned short* Ab = (const unsigned short*)Ap;

    auto stageOp = [&](const unsigned short* G, int rc0, int kt, char* opBase, int buf) {
        const int k0 = kt * TK;
        #pragma unroll
        for (int i = 0; i < 4; ++i)
            gload16(G + (size_t)(rc0 + srow[i]) * K + k0 + sq[i] * 8,
                    opBase + buf * 16384 + (i * 256 + wave * 64) * 16);
    };

    // AF32 A reg-staging: thread owns rows rA, rA+64, f32 cols g*16..g*16+15
    const int rA = tid >> 2;
    const int g  = tid & 3;
    const int qp0 = (2 * g) ^ (rA & 7);       // phys quad for cols g*16..+7
    const int qp1 = (2 * g + 1) ^ (rA & 7);   // phys quad for cols g*16+8..+15
    float4 L[8];
    auto loadA = [&](int kt) {
        const float* p0 = Af + (size_t)(m0 + rA) * K + kt * TK + g * 16;
        const float* p1 = p0 + (size_t)64 * K;
        L[0] = *reinterpret_cast<const float4*>(p0);
        L[1] = *reinterpret_cast<const float4*>(p0 + 4);
        L[2] = *reinterpret_cast<const float4*>(p0 + 8);
        L[3] = *reinterpret_cast<const float4*>(p0 + 12);
        L[4] = *reinterpret_cast<const float4*>(p1);
        L[5] = *reinterpret_cast<const float4*>(p1 + 4);
        L[6] = *reinterpret_cast<const float4*>(p1 + 8);
        L[7] = *reinterpret_cast<const float4*>(p1 + 12);
    };
    auto writeA = [&](int buf) {
        #pragma unroll
        for (int r = 0; r < 2; ++r) {
            const float4 f0 = L[r * 4 + 0], f1 = L[r * 4 + 1];
            const float4 f2 = L[r * 4 + 2], f3 = L[r * 4 + 3];
            uint4e a, b;
            a[0] = pkbf(f0.x, f0.y); a[1] = pkbf(f0.z, f0.w);
            a[2] = pkbf(f1.x, f1.y); a[3] = pkbf(f1.z, f1.w);
            b[0] = pkbf(f2.x, f2.y); b[1] = pkbf(f2.z, f2.w);
            b[2] = pkbf(f3.x, f3.y); b[3] = pkbf(f3.z, f3.w);
            char* rowb = AsB + buf * 16384 + (rA + r * 64) * 128;
            *reinterpret_cast<uint4e*>(rowb + qp0 * 16) = a;
            *reinterpret_cast<uint4e*>(rowb + qp1 * 16) = b;
        }
    };

    f32x4 acc[4][4] = {};

    // prologue: tile 0 into buffer 0
    stageOp(Bt, n0, 0, BsB, 0);
    if (AF32) { loadA(0); writeA(0); }
    else       stageOp(Ab, m0, 0, AsB, 0);
    __syncthreads();

    const int nk = K / TK;
    for (int kt = 0; kt < nk; ++kt) {
        const int cur = kt & 1, nxt = cur ^ 1;

        if (kt + 1 < nk) {
            stageOp(Bt, n0, kt + 1, BsB, nxt);
            if (AF32) loadA(kt + 1);
            else      stageOp(Ab, m0, kt + 1, AsB, nxt);
        }

        #pragma unroll
        for (int ks = 0; ks < 2; ++ks) {
            short8 af[4], bfr[4];
            #pragma unroll
            for (int mi = 0; mi < 4; ++mi) {
                const int row = wr * 64 + mi * 16 + lrow;
                const int qp = (ks * 4 + lkg) ^ (lrow & 7);
                af[mi] = *reinterpret_cast<const short8*>(&As[cur][row][qp * 8]);
            }
            #pragma unroll
            for (int ni = 0; ni < 4; ++ni) {
                const int row = wc * 64 + ni * 16 + lrow;
                const int qp = (ks * 4 + lkg) ^ (lrow & 7);
                bfr[ni] = *reinterpret_cast<const short8*>(&Bs[cur][row][qp * 8]);
            }
            #pragma unroll
            for (int mi = 0; mi < 4; ++mi)
                #pragma unroll
                for (int ni = 0; ni < 4; ++ni)
                    acc[mi][ni] = __builtin_amdgcn_mfma_f32_16x16x32_bf16(
                        af[mi], bfr[ni], acc[mi][ni], 0, 0, 0);
        }

        if (AF32 && kt + 1 < nk) writeA(nxt);

        __syncthreads();   // single barrier per K-step
    }

    #pragma unroll
    for (int mi = 0; mi < 4; ++mi)
        #pragma unroll
        for (int ni = 0; ni < 4; ++ni)
            #pragma unroll
            for (int r = 0; r < 4; ++r)
                Cb[(size_t)(m0 + wr * 64 + mi * 16 + lkg * 4 + r) * Nc
                   + (n0 + wc * 64 + ni * 16 + lrow)] = f2bf(acc[mi][ni][r]);
}

// ---------------- CSR gather-aggregate (bf16 X), fused epilogues ----------------
// One wave per node; lane owns DIM/64 contiguous elems; 4-edge unroll.
// LAYER1: acc = sum iso[src]*X[src]; out_bf = bf16(elu(acc*isi + b1) * iso[node])
// else:   acc = sum X[src];          out_f  = acc*isi + b2

template<int DIM, bool LAYER1>
__global__ __launch_bounds__(256) void aggregate(
    const int* __restrict__ row_start, const int* __restrict__ eidx,
    const unsigned short* __restrict__ Xb, const float* __restrict__ isi,
    const float* __restrict__ iso, const float* __restrict__ bias,
    unsigned short* __restrict__ out_bf, float* __restrict__ out_f)
{
    constexpr int F = DIM / 64;           // 8 (HID) or 4 (OUTD)
    using VecT = typename VecSel<F>::T;
    const int node = blockIdx.x * 4 + (threadIdx.x >> 6);
    const int lane = threadIdx.x & 63;

    const int beg = row_start[node];
    const int end = row_start[node + 1];
    const unsigned short* base = Xb + lane * F;

    float acc[F] = {};
    int e = beg;
    for (; e + 3 < end; e += 4) {
        int i0 = eidx[e], i1 = eidx[e + 1], i2 = eidx[e + 2], i3 = eidx[e + 3];
        float s0 = 1.f, s1 = 1.f, s2 = 1.f, s3 = 1.f;
        if (LAYER1) { s0 = iso[i0]; s1 = iso[i1]; s2 = iso[i2]; s3 = iso[i3]; }
        VecT v0 = *reinterpret_cast<const VecT*>(base + (size_t)i0 * DIM);
        VecT v1 = *reinterpret_cast<const VecT*>(base + (size_t)i1 * DIM);
        VecT v2 = *reinterpret_cast<const VecT*>(base + (size_t)i2 * DIM);
        VecT v3 = *reinterpret_cast<const VecT*>(base + (size_t)i3 * DIM);
        #pragma unroll
        for (int f = 0; f < F; ++f) {
            if (LAYER1) {
                acc[f] = fmaf(s0, bf2f(v0[f]), acc[f]);
                acc[f] = fmaf(s1, bf2f(v1[f]), acc[f]);
                acc[f] = fmaf(s2, bf2f(v2[f]), acc[f]);
                acc[f] = fmaf(s3, bf2f(v3[f]), acc[f]);
            } else {
                acc[f] += bf2f(v0[f]); acc[f] += bf2f(v1[f]);
                acc[f] += bf2f(v2[f]); acc[f] += bf2f(v3[f]);
            }
        }
    }
    for (; e < end; ++e) {
        int i0 = eidx[e];
        float s0 = LAYER1 ? iso[i0] : 1.f;
        VecT v0 = *reinterpret_cast<const VecT*>(base + (size_t)i0 * DIM);
        #pragma unroll
        for (int f = 0; f < F; ++f)
            acc[f] = LAYER1 ? fmaf(s0, bf2f(v0[f]), acc[f]) : acc[f] + bf2f(v0[f]);
    }

    const float si = isi[node];
    float bv[F];
    #pragma unroll
    for (int q = 0; q < F / 4; ++q)
        *reinterpret_cast<float4*>(&bv[q * 4]) =
            *reinterpret_cast<const float4*>(bias + lane * F + q * 4);

    if (LAYER1) {
        const float so = iso[node];
        short8 o;
        #pragma unroll
        for (int f = 0; f < F; ++f) {
            float v = acc[f] * si + bv[f];
            v = v > 0.f ? v : expm1f(v);
            o[f] = (short)f2bf(v * so);
        }
        *reinterpret_cast<short8*>(out_bf + (size_t)node * DIM + lane * F) = o;
    } else {
        #pragma unroll
        for (int q = 0; q < F / 4; ++q) {
            float4 v = make_float4(acc[q * 4 + 0] * si + bv[q * 4 + 0],
                                   acc[q * 4 + 1] * si + bv[q * 4 + 1],
                                   acc[q * 4 + 2] * si + bv[q * 4 + 2],
                                   acc[q * 4 + 3] * si + bv[q * 4 + 3]);
            *reinterpret_cast<float4*>(out_f + (size_t)node * DIM + lane * F + q * 4) = v;
        }
    }
}

// ---------------- launch ----------------

extern "C" void kernel_launch(void* const* d_in, const int* in_sizes, int n_in,
                              void* d_out, int out_size, void* d_ws, size_t ws_size,
                              hipStream_t stream) {
    const float* h  = (const float*)d_in[0];
    const float* W1 = (const float*)d_in[1];
    const float* b1 = (const float*)d_in[2];
    const float* W2 = (const float*)d_in[3];
    const float* b2 = (const float*)d_in[4];
    const int*   src = (const int*)d_in[5];
    const int*   dst = (const int*)d_in[6];

    const int N = in_sizes[0] / IN_DIM;   // 65536
    const int E = in_sizes[5];            // 524288
    float* out = (float*)d_out;

    // ---- workspace layout ----
    int* dego      = (int*)d_ws;                   // N
    int* degi      = dego + N;                     // N
    int* excl      = degi + N;                     // N
    int* partials  = excl + N;                     // 256
    int* row_start = partials + 256;               // N+1 (pad to N+64)
    int* cursor    = row_start + N + 64;           // N
    int* eidx      = cursor + N;                   // E
    float* iso     = (float*)(eidx + E);           // N
    float* isi     = iso + N;                      // N
    unsigned short* W1t = (unsigned short*)(isi + N);      // IN_DIM*HID
    unsigned short* W2t = W1t + (size_t)IN_DIM * HID;      // HID*OUTD
    unsigned short* X1b = W2t + (size_t)HID * OUTD;        // N*HID bf16 (67MB)
    unsigned short* X2b = X1b;                             // alias (X1 dead before gemm2 write)
    unsigned short* R2h = X1b + (size_t)N * HID;           // N*HID bf16 (67MB) — x1s

    hipMemsetAsync(dego, 0, sizeof(int) * (size_t)2 * N, stream);

    deg_kernel<<<(E + 255) / 256, 256, 0, stream>>>(src, dst, dego, degi, E);
    invsqrt_kernel<<<(N + 255) / 256, 256, 0, stream>>>(dego, degi, iso, isi, N);

    // CSR by dst
    scan_block<<<N / 256, 256, 0, stream>>>(degi, excl, partials);
    scan_partials<<<1, 256, 0, stream>>>(partials);
    scan_add<<<N / 256, 256, 0, stream>>>(excl, partials, degi, row_start, cursor, N);
    csr_fill<<<(E + 255) / 256, 256, 0, stream>>>(src, dst, cursor, eidx, E);

    // weights -> bf16 transposed
    transpose_cvt<<<(IN_DIM * HID + 255) / 256, 256, 0, stream>>>(W1, W1t, IN_DIM, HID);
    transpose_cvt<<<(HID * OUTD + 255) / 256, 256, 0, stream>>>(W2, W2t, HID, OUTD);

    // Layer 1: X1b = bf16(h @ W1) [cvt fused]; agg applies iso[src] during gather
    gemm_bf16_mfma<1><<<(N / TM) * (HID / TN), 256, 0, stream>>>(
        h, W1t, X1b, N, IN_DIM, HID);
    aggregate<HID, true><<<N / 4, 256, 0, stream>>>(
        row_start, eidx, X1b, isi, iso, b1, R2h, nullptr);

    // Layer 2: X2b = bf16(R2h @ W2) ; out = agg(X2b)*isi + b2
    gemm_bf16_mfma<0><<<(N / TM) * (OUTD / TN), 256, 0, stream>>>(
        R2h, W2t, X2b, N, HID, OUTD);
    aggregate<OUTD, false><<<N / 4, 256, 0, stream>>>(
        row_start, eidx, X2b, isi, iso, b2, nullptr, out);
}

// Round 11
// 427.583 us; speedup vs baseline: 1.0366x; 1.0097x over previous
//
#include <hip/hip_runtime.h>
#include <hip/hip_bf16.h>

#define IN_DIM 1024
#define HID 512
#define OUTD 256

typedef __attribute__((ext_vector_type(8))) short short8;
typedef __attribute__((ext_vector_type(4))) float f32x4;
typedef __attribute__((ext_vector_type(8))) unsigned short ushort8e;
typedef __attribute__((ext_vector_type(4))) unsigned short ushort4e;
typedef __attribute__((ext_vector_type(4))) unsigned int uint4e;

template<int F> struct VecSel;
template<> struct VecSel<8> { using T = ushort8e; };
template<> struct VecSel<4> { using T = ushort4e; };

// ---------------- helpers ----------------

__device__ inline unsigned short f2bf(float f) {
    union { float f; unsigned u; } v; v.f = f;
    unsigned r = (v.u + 0x7FFF + ((v.u >> 16) & 1)) >> 16;  // RNE
    return (unsigned short)r;
}

__device__ inline float bf2f(unsigned short u) {
    union { unsigned u; float f; } v; v.u = ((unsigned)u) << 16; return v.f;
}

// ---------------- degree / norm ----------------

__global__ void deg_kernel(const int* __restrict__ src, const int* __restrict__ dst,
                           int* __restrict__ dego, int* __restrict__ degi, int E) {
    int i = blockIdx.x * blockDim.x + threadIdx.x;
    if (i < E) {
        atomicAdd(&dego[src[i]], 1);
        atomicAdd(&degi[dst[i]], 1);
    }
}

__global__ void invsqrt_kernel(const int* __restrict__ dego, const int* __restrict__ degi,
                               float* __restrict__ iso, float* __restrict__ isi, int n) {
    int i = blockIdx.x * blockDim.x + threadIdx.x;
    if (i < n) {
        iso[i] = rsqrtf(fmaxf((float)dego[i], 1.0f));
        isi[i] = rsqrtf(fmaxf((float)degi[i], 1.0f));
    }
}

// ---------------- exclusive scan over N=65536 (256 blocks x 256) ----------------

__global__ __launch_bounds__(256) void scan_block(const int* __restrict__ deg,
                                                  int* __restrict__ excl,
                                                  int* __restrict__ partials) {
    __shared__ int tmp[256];
    int tid = threadIdx.x;
    int i = blockIdx.x * 256 + tid;
    int v = deg[i];
    tmp[tid] = v;
    __syncthreads();
    #pragma unroll
    for (int off = 1; off < 256; off <<= 1) {
        int t = (tid >= off) ? tmp[tid - off] : 0;
        __syncthreads();
        tmp[tid] += t;
        __syncthreads();
    }
    excl[i] = tmp[tid] - v;
    if (tid == 255) partials[blockIdx.x] = tmp[255];
}

__global__ __launch_bounds__(256) void scan_partials(int* __restrict__ partials) {
    __shared__ int tmp[256];
    int tid = threadIdx.x;
    int v = partials[tid];
    tmp[tid] = v;
    __syncthreads();
    #pragma unroll
    for (int off = 1; off < 256; off <<= 1) {
        int t = (tid >= off) ? tmp[tid - off] : 0;
        __syncthreads();
        tmp[tid] += t;
        __syncthreads();
    }
    partials[tid] = tmp[tid] - v;   // exclusive
}

__global__ __launch_bounds__(256) void scan_add(const int* __restrict__ excl,
                                                const int* __restrict__ partials,
                                                const int* __restrict__ deg,
                                                int* __restrict__ row_start,
                                                int* __restrict__ cursor, int n) {
    int i = blockIdx.x * 256 + threadIdx.x;
    int v = excl[i] + partials[blockIdx.x];
    row_start[i] = v;
    cursor[i] = v;
    if (i == n - 1) row_start[n] = v + deg[i];
}

__global__ void csr_fill(const int* __restrict__ src, const int* __restrict__ dst,
                         int* __restrict__ cursor, int* __restrict__ eidx, int E) {
    int e = blockIdx.x * blockDim.x + threadIdx.x;
    if (e < E) {
        int pos = atomicAdd(&cursor[dst[e]], 1);
        eidx[pos] = src[e];
    }
}

// ---------------- weight transpose+cvt ----------------

__global__ void transpose_cvt(const float* __restrict__ W, unsigned short* __restrict__ Wt,
                              int K, int N) {
    int i = blockIdx.x * 256 + threadIdx.x;
    if (i < N * K) {
        int n = i / K, k = i - n * K;
        Wt[i] = f2bf(W[(size_t)k * N + n]);
    }
}

// ---------------- bf16 MFMA GEMM: C = A[M,K] @ Bt[Nc,K]^T, bf16 output ----------------
// BK=64 double-buffered single-barrier K-loop, XCD-aware block swizzle.
// ALL-REGISTER staging (T14): loads to regs at iter top, ds_write after MFMA.
// Every vmem op is reg-consumed before the barrier -> barrier vmcnt-drain is a
// no-op and load latency hides under the ds_read+MFMA phase. No gload_lds.
// AF32=1: A f32 -> bf16 cvt in staging (no scale; scale moved to aggregate).

#define TM 128
#define TN 128
#define TK 64
#define NXCD 8

template<int AF32>
__global__ __launch_bounds__(256) void gemm_bf16_mfma(
    const void* __restrict__ Ap, const unsigned short* __restrict__ Bt,
    unsigned short* __restrict__ Cb, int M, int K, int Nc)
{
    __shared__ unsigned short As[2][TM][TK];   // 2 x 16 KB
    __shared__ unsigned short Bs[2][TN][TK];   // 2 x 16 KB

    const int tid  = threadIdx.x;
    const int lane = tid & 63;
    const int wave = tid >> 6;
    const int wr = wave >> 1, wc = wave & 1;
    const int lrow = lane & 15;
    const int lkg  = lane >> 4;

    // ---- XCD swizzle: siblings sharing an A-panel run on the same XCD ----
    const int nwg = gridDim.x;                // divisible by 8
    const int per = nwg / NXCD;
    const int lin = blockIdx.x;
    const int newlin = (lin % NXCD) * per + lin / NXCD;
    const int ncb = Nc / TN;
    const int m0 = (newlin / ncb) * TM;
    const int n0 = (newlin % ncb) * TN;

    char* AsB = (char*)&As[0][0][0];
    char* BsB = (char*)&Bs[0][0][0];

    const float* Af = (const float*)Ap;
    const unsigned short* Ab = (const unsigned short*)Ap;

    // ---- bf16 operand reg-staging: thread owns row rS (0..127), half hS ----
    // quads qS = hS*4+j ; phys slot qp = q ^ (row&7) (involution, both sides)
    const int rS = tid >> 1;
    const int hS = tid & 1;
    int qS[4], qpS[4];
    #pragma unroll
    for (int j = 0; j < 4; ++j) { qS[j] = hS * 4 + j; qpS[j] = qS[j] ^ (rS & 7); }

    uint4e bReg[4], aRegB[4];
    auto loadB = [&](int kt) {
        const unsigned short* p = Bt + (size_t)(n0 + rS) * K + kt * TK;
        #pragma unroll
        for (int j = 0; j < 4; ++j)
            bReg[j] = *reinterpret_cast<const uint4e*>(p + qS[j] * 8);
    };
    auto writeB = [&](int buf) {
        char* rowb = BsB + buf * 16384 + rS * 128;
        #pragma unroll
        for (int j = 0; j < 4; ++j)
            *reinterpret_cast<uint4e*>(rowb + qpS[j] * 16) = bReg[j];
    };
    auto loadAb = [&](int kt) {
        const unsigned short* p = Ab + (size_t)(m0 + rS) * K + kt * TK;
        #pragma unroll
        for (int j = 0; j < 4; ++j)
            aRegB[j] = *reinterpret_cast<const uint4e*>(p + qS[j] * 8);
    };
    auto writeAb = [&](int buf) {
        char* rowb = AsB + buf * 16384 + rS * 128;
        #pragma unroll
        for (int j = 0; j < 4; ++j)
            *reinterpret_cast<uint4e*>(rowb + qpS[j] * 16) = aRegB[j];
    };

    // ---- f32 A reg-staging: thread owns rows rA, rA+64, f32 cols g*16..+15 ----
    const int rA = tid >> 2;
    const int g  = tid & 3;
    const int qp0 = (2 * g) ^ (rA & 7);
    const int qp1 = (2 * g + 1) ^ (rA & 7);
    float4 L[8];
    auto loadA = [&](int kt) {
        const float* p0 = Af + (size_t)(m0 + rA) * K + kt * TK + g * 16;
        const float* p1 = p0 + (size_t)64 * K;
        L[0] = *reinterpret_cast<const float4*>(p0);
        L[1] = *reinterpret_cast<const float4*>(p0 + 4);
        L[2] = *reinterpret_cast<const float4*>(p0 + 8);
        L[3] = *reinterpret_cast<const float4*>(p0 + 12);
        L[4] = *reinterpret_cast<const float4*>(p1);
        L[5] = *reinterpret_cast<const float4*>(p1 + 4);
        L[6] = *reinterpret_cast<const float4*>(p1 + 8);
        L[7] = *reinterpret_cast<const float4*>(p1 + 12);
    };
    auto writeA = [&](int buf) {
        #pragma unroll
        for (int r = 0; r < 2; ++r) {
            const float4 f0 = L[r * 4 + 0], f1 = L[r * 4 + 1];
            const float4 f2 = L[r * 4 + 2], f3 = L[r * 4 + 3];
            short8 k0v, k1v;
            k0v[0] = (short)f2bf(f0.x); k0v[1] = (short)f2bf(f0.y);
            k0v[2] = (short)f2bf(f0.z); k0v[3] = (short)f2bf(f0.w);
            k0v[4] = (short)f2bf(f1.x); k0v[5] = (short)f2bf(f1.y);
            k0v[6] = (short)f2bf(f1.z); k0v[7] = (short)f2bf(f1.w);
            k1v[0] = (short)f2bf(f2.x); k1v[1] = (short)f2bf(f2.y);
            k1v[2] = (short)f2bf(f2.z); k1v[3] = (short)f2bf(f2.w);
            k1v[4] = (short)f2bf(f3.x); k1v[5] = (short)f2bf(f3.y);
            k1v[6] = (short)f2bf(f3.z); k1v[7] = (short)f2bf(f3.w);
            char* rowb = AsB + buf * 16384 + (rA + r * 64) * 128;
            *reinterpret_cast<short8*>(rowb + qp0 * 16) = k0v;
            *reinterpret_cast<short8*>(rowb + qp1 * 16) = k1v;
        }
    };

    f32x4 acc[4][4] = {};

    // prologue: tile 0 into buffer 0
    loadB(0);
    if (AF32) loadA(0); else loadAb(0);
    writeB(0);
    if (AF32) writeA(0); else writeAb(0);
    __syncthreads();

    const int nk = K / TK;
    for (int kt = 0; kt < nk; ++kt) {
        const int cur = kt & 1, nxt = cur ^ 1;

        // issue next tile's loads to REGISTERS (latency hides under MFMA phase)
        if (kt + 1 < nk) {
            loadB(kt + 1);
            if (AF32) loadA(kt + 1); else loadAb(kt + 1);
        }

        #pragma unroll
        for (int ks = 0; ks < 2; ++ks) {
            short8 af[4], bfr[4];
            #pragma unroll
            for (int mi = 0; mi < 4; ++mi) {
                const int row = wr * 64 + mi * 16 + lrow;
                const int qp = (ks * 4 + lkg) ^ (lrow & 7);
                af[mi] = *reinterpret_cast<const short8*>(&As[cur][row][qp * 8]);
            }
            #pragma unroll
            for (int ni = 0; ni < 4; ++ni) {
                const int row = wc * 64 + ni * 16 + lrow;
                const int qp = (ks * 4 + lkg) ^ (lrow & 7);
                bfr[ni] = *reinterpret_cast<const short8*>(&Bs[cur][row][qp * 8]);
            }
            #pragma unroll
            for (int mi = 0; mi < 4; ++mi)
                #pragma unroll
                for (int ni = 0; ni < 4; ++ni)
                    acc[mi][ni] = __builtin_amdgcn_mfma_f32_16x16x32_bf16(
                        af[mi], bfr[ni], acc[mi][ni], 0, 0, 0);
        }

        // write next tile into LDS after MFMA (loads have landed by now)
        if (kt + 1 < nk) {
            writeB(nxt);
            if (AF32) writeA(nxt); else writeAb(nxt);
        }

        __syncthreads();   // single barrier; vmcnt already drained by reg deps
    }

    #pragma unroll
    for (int mi = 0; mi < 4; ++mi)
        #pragma unroll
        for (int ni = 0; ni < 4; ++ni)
            #pragma unroll
            for (int r = 0; r < 4; ++r)
                Cb[(size_t)(m0 + wr * 64 + mi * 16 + lkg * 4 + r) * Nc
                   + (n0 + wc * 64 + ni * 16 + lrow)] = f2bf(acc[mi][ni][r]);
}

// ---------------- CSR gather-aggregate (bf16 X), fused epilogues ----------------
// One wave per node; lane owns DIM/64 contiguous elems; 4-edge unroll.
// LAYER1: acc = sum iso[src]*X[src]; out_bf = bf16(elu(acc*isi + b1) * iso[node])
// else:   acc = sum X[src];          out_f  = acc*isi + b2

template<int DIM, bool LAYER1>
__global__ __launch_bounds__(256) void aggregate(
    const int* __restrict__ row_start, const int* __restrict__ eidx,
    const unsigned short* __restrict__ Xb, const float* __restrict__ isi,
    const float* __restrict__ iso, const float* __restrict__ bias,
    unsigned short* __restrict__ out_bf, float* __restrict__ out_f)
{
    constexpr int F = DIM / 64;           // 8 (HID) or 4 (OUTD)
    using VecT = typename VecSel<F>::T;
    const int node = blockIdx.x * 4 + (threadIdx.x >> 6);
    const int lane = threadIdx.x & 63;

    const int beg = row_start[node];
    const int end = row_start[node + 1];
    const unsigned short* base = Xb + lane * F;

    float acc[F] = {};
    int e = beg;
    for (; e + 3 < end; e += 4) {
        int i0 = eidx[e], i1 = eidx[e + 1], i2 = eidx[e + 2], i3 = eidx[e + 3];
        float s0 = 1.f, s1 = 1.f, s2 = 1.f, s3 = 1.f;
        if (LAYER1) { s0 = iso[i0]; s1 = iso[i1]; s2 = iso[i2]; s3 = iso[i3]; }
        VecT v0 = *reinterpret_cast<const VecT*>(base + (size_t)i0 * DIM);
        VecT v1 = *reinterpret_cast<const VecT*>(base + (size_t)i1 * DIM);
        VecT v2 = *reinterpret_cast<const VecT*>(base + (size_t)i2 * DIM);
        VecT v3 = *reinterpret_cast<const VecT*>(base + (size_t)i3 * DIM);
        #pragma unroll
        for (int f = 0; f < F; ++f) {
            if (LAYER1) {
                acc[f] = fmaf(s0, bf2f(v0[f]), acc[f]);
                acc[f] = fmaf(s1, bf2f(v1[f]), acc[f]);
                acc[f] = fmaf(s2, bf2f(v2[f]), acc[f]);
                acc[f] = fmaf(s3, bf2f(v3[f]), acc[f]);
            } else {
                acc[f] += bf2f(v0[f]); acc[f] += bf2f(v1[f]);
                acc[f] += bf2f(v2[f]); acc[f] += bf2f(v3[f]);
            }
        }
    }
    for (; e < end; ++e) {
        int i0 = eidx[e];
        float s0 = LAYER1 ? iso[i0] : 1.f;
        VecT v0 = *reinterpret_cast<const VecT*>(base + (size_t)i0 * DIM);
        #pragma unroll
        for (int f = 0; f < F; ++f)
            acc[f] = LAYER1 ? fmaf(s0, bf2f(v0[f]), acc[f]) : acc[f] + bf2f(v0[f]);
    }

    const float si = isi[node];
    float bv[F];
    #pragma unroll
    for (int q = 0; q < F / 4; ++q)
        *reinterpret_cast<float4*>(&bv[q * 4]) =
            *reinterpret_cast<const float4*>(bias + lane * F + q * 4);

    if (LAYER1) {
        const float so = iso[node];
        short8 o;
        #pragma unroll
        for (int f = 0; f < F; ++f) {
            float v = acc[f] * si + bv[f];
            v = v > 0.f ? v : expm1f(v);
            o[f] = (short)f2bf(v * so);
        }
        *reinterpret_cast<short8*>(out_bf + (size_t)node * DIM + lane * F) = o;
    } else {
        #pragma unroll
        for (int q = 0; q < F / 4; ++q) {
            float4 v = make_float4(acc[q * 4 + 0] * si + bv[q * 4 + 0],
                                   acc[q * 4 + 1] * si + bv[q * 4 + 1],
                                   acc[q * 4 + 2] * si + bv[q * 4 + 2],
                                   acc[q * 4 + 3] * si + bv[q * 4 + 3]);
            *reinterpret_cast<float4*>(out_f + (size_t)node * DIM + lane * F + q * 4) = v;
        }
    }
}

// ---------------- launch ----------------

extern "C" void kernel_launch(void* const* d_in, const int* in_sizes, int n_in,
                              void* d_out, int out_size, void* d_ws, size_t ws_size,
                              hipStream_t stream) {
    const float* h  = (const float*)d_in[0];
    const float* W1 = (const float*)d_in[1];
    const float* b1 = (const float*)d_in[2];
    const float* W2 = (const float*)d_in[3];
    const float* b2 = (const float*)d_in[4];
    const int*   src = (const int*)d_in[5];
    const int*   dst = (const int*)d_in[6];

    const int N = in_sizes[0] / IN_DIM;   // 65536
    const int E = in_sizes[5];            // 524288
    float* out = (float*)d_out;

    // ---- workspace layout ----
    int* dego      = (int*)d_ws;                   // N
    int* degi      = dego + N;                     // N
    int* excl      = degi + N;                     // N
    int* partials  = excl + N;                     // 256
    int* row_start = partials + 256;               // N+1 (pad to N+64)
    int* cursor    = row_start + N + 64;           // N
    int* eidx      = cursor + N;                   // E
    float* iso     = (float*)(eidx + E);           // N
    float* isi     = iso + N;                      // N
    unsigned short* W1t = (unsigned short*)(isi + N);      // IN_DIM*HID
    unsigned short* W2t = W1t + (size_t)IN_DIM * HID;      // HID*OUTD
    unsigned short* X1b = W2t + (size_t)HID * OUTD;        // N*HID bf16 (67MB)
    unsigned short* X2b = X1b;                             // alias (X1 dead before gemm2 write)
    unsigned short* R2h = X1b + (size_t)N * HID;           // N*HID bf16 (67MB) — x1s

    hipMemsetAsync(dego, 0, sizeof(int) * (size_t)2 * N, stream);

    deg_kernel<<<(E + 255) / 256, 256, 0, stream>>>(src, dst, dego, degi, E);
    invsqrt_kernel<<<(N + 255) / 256, 256, 0, stream>>>(dego, degi, iso, isi, N);

    // CSR by dst
    scan_block<<<N / 256, 256, 0, stream>>>(degi, excl, partials);
    scan_partials<<<1, 256, 0, stream>>>(partials);
    scan_add<<<N / 256, 256, 0, stream>>>(excl, partials, degi, row_start, cursor, N);
    csr_fill<<<(E + 255) / 256, 256, 0, stream>>>(src, dst, cursor, eidx, E);

    // weights -> bf16 transposed
    transpose_cvt<<<(IN_DIM * HID + 255) / 256, 256, 0, stream>>>(W1, W1t, IN_DIM, HID);
    transpose_cvt<<<(HID * OUTD + 255) / 256, 256, 0, stream>>>(W2, W2t, HID, OUTD);

    // Layer 1: X1b = bf16(h @ W1) [cvt fused]; agg applies iso[src] during gather
    gemm_bf16_mfma<1><<<(N / TM) * (HID / TN), 256, 0, stream>>>(
        h, W1t, X1b, N, IN_DIM, HID);
    aggregate<HID, true><<<N / 4, 256, 0, stream>>>(
        row_start, eidx, X1b, isi, iso, b1, R2h, nullptr);

    // Layer 2: X2b = bf16(R2h @ W2) ; out = agg(X2b)*isi + b2
    gemm_bf16_mfma<0><<<(N / TM) * (OUTD / TN), 256, 0, stream>>>(
        R2h, W2t, X2b, N, HID, OUTD);
    aggregate<OUTD, false><<<N / 4, 256, 0, stream>>>(
        row_start, eidx, X2b, isi, iso, b2, nullptr, out);
}